// Round 12
// baseline (618.129 us; speedup 1.0000x reference)
//
#include <hip/hip_runtime.h>

// LocalizeAttention3D: out[bh,(y,x,z), f=(fi,fj,fk), :] = x[bh,(y+fi-1,x+fj-1,z+fk-1), :]
// zero-padded outside the 24^3 grid. d=16 floats = 4 float4 per voxel.
//
// Round 12: MEASUREMENT ROUND (upgraded SNR). Identical LDS-staged kernel
// launched FOUR times (idempotent => correctness unchanged).
// dur_us(this) - dur_us(r8=397.4) = 3k, where k = one kernel dispatch's true
// duration. Separates kernel time from the ~243us+ harness poison-fill
// overhead that dominates dur_us.

#define NF 27

typedef float4 f4;

__global__ __launch_bounds__(256) void localize3d_lds(
    const f4* __restrict__ in,   // [bh, 13824, 4]
    f4* __restrict__ out)        // [bh, 13824, 27, 4]
{
    __shared__ f4 slab[1872];    // (3*6*26) voxels * 4 float4 = 29,952 B

    unsigned bid = blockIdx.x;          // 0..2303
    unsigned xt = bid % 6u;
    unsigned y  = (bid / 6u) % 24u;
    unsigned bh = bid / 144u;
    unsigned x0 = xt * 4u;

    // ---- stage slab (zero halo) ----
    for (unsigned s = threadIdx.x; s < 1872u; s += 256u) {
        unsigned dd4 = s & 3u;
        unsigned sv  = s >> 2;              // 0..467
        unsigned sz  = sv % 26u;
        unsigned sx  = (sv / 26u) % 6u;
        unsigned sy  = sv / 156u;
        int gy = (int)y  + (int)sy - 1;
        int gx = (int)x0 + (int)sx - 1;
        int gz = (int)sz - 1;
        f4 v = make_float4(0.f, 0.f, 0.f, 0.f);
        if ((unsigned)gy < 24u && (unsigned)gx < 24u && (unsigned)gz < 24u) {
            unsigned q = ((bh * 24u + (unsigned)gy) * 24u + (unsigned)gx) * 24u + (unsigned)gz;
            v = in[q * 4u + dd4];
        }
        slab[s] = v;
    }
    __syncthreads();

    // ---- write 10368 contiguous float4s: o' = t + k*256, k = 0..40 (last: t<128) ----
    unsigned t   = threadIdx.x;
    unsigned dd4 = t & 3u;
    unsigned r0  = t >> 2;                 // 0..63
    unsigned lv  = r0 / 27u;               // 0..2
    unsigned f   = r0 - lv * 27u;
    unsigned lx  = 0u;
    unsigned lz  = lv;                     // lv < 24 here

    unsigned q0 = ((bh * 24u + y) * 24u + x0) * 24u;   // block's first voxel
    unsigned ob = q0 * 108u + t;           // output float4 index

#define BODY() do {                                                     \
        unsigned fi = (f * 57u) >> 9;      /* f/9  for f<27 */          \
        unsigned f3 = (f * 171u) >> 9;     /* f/3  for f<27 */          \
        unsigned fj = f3 - fi * 3u;                                     \
        unsigned fk = f - f3 * 3u;                                      \
        unsigned sv = (fi * 6u + lx + fj) * 26u + (lz + fk);            \
        out[ob] = slab[sv * 4u + dd4];                                  \
        ob += 256u;                                                     \
        f += 10u;                          /* r' += 64 = 2*27 + 10 */   \
        unsigned inc = 2u;                                              \
        if (f >= 27u) { f -= 27u; inc = 3u; }                           \
        lz += inc;                                                      \
        if (lz >= 24u) { lz -= 24u; lx += 1u; }                         \
    } while (0)

#pragma unroll 4
    for (int k = 0; k < 40; ++k) { BODY(); }
    if (t < 128u) { BODY(); }              // 10368 = 40*256 + 128
#undef BODY
}

extern "C" void kernel_launch(void* const* d_in, const int* in_sizes, int n_in,
                              void* d_out, int out_size, void* d_ws, size_t ws_size,
                              hipStream_t stream) {
    const f4* in = (const f4*)d_in[0];
    f4* out = (f4*)d_out;
    // grid: 16 bh * 24 y * 6 x-tiles = 2304 blocks, each owns 96 voxels
    // PROBE: launch 4x (idempotent). dur_us - 397.4 == 3 * (one kernel's time).
    localize3d_lds<<<2304, 256, 0, stream>>>(in, out);
    localize3d_lds<<<2304, 256, 0, stream>>>(in, out);
    localize3d_lds<<<2304, 256, 0, stream>>>(in, out);
    localize3d_lds<<<2304, 256, 0, stream>>>(in, out);
}

// Round 13
// 397.261 us; speedup vs baseline: 1.5560x; 1.5560x over previous
//
#include <hip/hip_runtime.h>

// LocalizeAttention3D: out[bh,(y,x,z), f=(fi,fj,fk), :] = x[bh,(y+fi-1,x+fj-1,z+fk-1), :]
// zero-padded outside the 24^3 grid. d=16 floats = 4 float4 per voxel.
//
// FINAL (round 13): LDS-staged slab, single launch.
// Measured via the r12 4x-launch probe: one dispatch k ~= 73.6 us.
// Traffic: 382 MB stores + ~69 MB staged reads = 451 MB / 73.6 us = 6.13 TB/s
// ~= 97% of the demonstrated achievable fabric BW (fill kernel: 6.27-6.38 TB/s).
// Reported dur_us ~= 397 is dominated by ~324 us constant harness overhead
// (poison fills); controllable residual <= ~2.7%.

#define NF 27

typedef float4 f4;

__global__ __launch_bounds__(256) void localize3d_lds(
    const f4* __restrict__ in,   // [bh, 13824, 4]
    f4* __restrict__ out)        // [bh, 13824, 27, 4]
{
    __shared__ f4 slab[1872];    // (3*6*26) voxels * 4 float4 = 29,952 B

    unsigned bid = blockIdx.x;          // 0..2303
    unsigned xt = bid % 6u;
    unsigned y  = (bid / 6u) % 24u;
    unsigned bh = bid / 144u;
    unsigned x0 = xt * 4u;

    // ---- stage slab (zero halo) ----
    for (unsigned s = threadIdx.x; s < 1872u; s += 256u) {
        unsigned dd4 = s & 3u;
        unsigned sv  = s >> 2;              // 0..467
        unsigned sz  = sv % 26u;
        unsigned sx  = (sv / 26u) % 6u;
        unsigned sy  = sv / 156u;
        int gy = (int)y  + (int)sy - 1;
        int gx = (int)x0 + (int)sx - 1;
        int gz = (int)sz - 1;
        f4 v = make_float4(0.f, 0.f, 0.f, 0.f);
        if ((unsigned)gy < 24u && (unsigned)gx < 24u && (unsigned)gz < 24u) {
            unsigned q = ((bh * 24u + (unsigned)gy) * 24u + (unsigned)gx) * 24u + (unsigned)gz;
            v = in[q * 4u + dd4];
        }
        slab[s] = v;
    }
    __syncthreads();

    // ---- write 10368 contiguous float4s: o' = t + k*256, k = 0..40 (last: t<128) ----
    unsigned t   = threadIdx.x;
    unsigned dd4 = t & 3u;
    unsigned r0  = t >> 2;                 // 0..63
    unsigned lv  = r0 / 27u;               // 0..2
    unsigned f   = r0 - lv * 27u;
    unsigned lx  = 0u;
    unsigned lz  = lv;                     // lv < 24 here

    unsigned q0 = ((bh * 24u + y) * 24u + x0) * 24u;   // block's first voxel
    unsigned ob = q0 * 108u + t;           // output float4 index

#define BODY() do {                                                     \
        unsigned fi = (f * 57u) >> 9;      /* f/9  for f<27 */          \
        unsigned f3 = (f * 171u) >> 9;     /* f/3  for f<27 */          \
        unsigned fj = f3 - fi * 3u;                                     \
        unsigned fk = f - f3 * 3u;                                      \
        unsigned sv = (fi * 6u + lx + fj) * 26u + (lz + fk);            \
        out[ob] = slab[sv * 4u + dd4];                                  \
        ob += 256u;                                                     \
        f += 10u;                          /* r' += 64 = 2*27 + 10 */   \
        unsigned inc = 2u;                                              \
        if (f >= 27u) { f -= 27u; inc = 3u; }                           \
        lz += inc;                                                      \
        if (lz >= 24u) { lz -= 24u; lx += 1u; }                         \
    } while (0)

#pragma unroll 4
    for (int k = 0; k < 40; ++k) { BODY(); }
    if (t < 128u) { BODY(); }              // 10368 = 40*256 + 128
#undef BODY
}

extern "C" void kernel_launch(void* const* d_in, const int* in_sizes, int n_in,
                              void* d_out, int out_size, void* d_ws, size_t ws_size,
                              hipStream_t stream) {
    const f4* in = (const f4*)d_in[0];
    f4* out = (f4*)d_out;
    // grid: 16 bh * 24 y * 6 x-tiles = 2304 blocks, each owns 96 voxels
    localize3d_lds<<<2304, 256, 0, stream>>>(in, out);
}